// Round 7
// baseline (811.043 us; speedup 1.0000x reference)
//
#include <hip/hip_runtime.h>

// Problem constants: L=2048, B=32, D=512
#define LL 2048
#define BB 32
#define DD 512
#define NN (3 * DD)
#define KK (DD)

#define SCH 16                 /* timesteps per chunk */
#define NCH (LL / SCH)         /* 128 chunks          */

typedef short bf16x8 __attribute__((ext_vector_type(8)));
typedef float f32x4 __attribute__((ext_vector_type(4)));

__device__ __forceinline__ unsigned short f2bf(float f) {
  unsigned u = __builtin_bit_cast(unsigned, f);
  u += 0x7fffu + ((u >> 16) & 1u);   // round-to-nearest-even
  return (unsigned short)(u >> 16);
}

// ------- kernel 1: W (D x 3D fp32) -> Wt (bf16, [o'=g*D+d][k] N-major) -----
// Verbatim from the verified baseline.
__global__ __launch_bounds__(256) void cvt_w_kernel(const float* __restrict__ W,
                                                    unsigned short* __restrict__ Wt) {
  int j = blockIdx.x * 256 + threadIdx.x;      // 786432 threads, exact
  int i  = j & (KK - 1);                       // k 0..511
  int op = j >> 9;                             // o' 0..1535
  int g  = op >> 9;                            // gate 0..2
  int dd = op & (DD - 1);                      // d 0..511
  Wt[j] = f2bf(W[(size_t)i * NN + dd * 3 + g]);
}

// ------------------- kernel 2: fused GEMM + sequential scan ----------------
// 512 blocks x 448 thr (7 waves). Block = (batch b, 32-channel group d0).
// Waves 0-5: per chunk of 16 timesteps, reg-stage x fp32->bf16 into swizzled
// LDS, then MFMA U-chunk (16 x 96 = 6 16x16 tiles, one per wave, K=512) with
// W-fragments preloaded in registers (stationary). Wave 6: consumes U-chunk
// (2-chunk pipeline lag), runs the serial recurrence for 32 channels.
// LDS races: at super-step s, writes hit xbuf[s&1] / ubuf[(s-1)&1]; reads hit
// xbuf[(s-1)&1] / ubuf[(s-2)&1] — always the opposite buffer.
__global__ __launch_bounds__(448, 1) void fused_kernel(
    const float* __restrict__ x, const unsigned short* __restrict__ Wt,
    const float* __restrict__ wc, const float* __restrict__ bias,
    float* __restrict__ out) {
  __shared__ __align__(16) unsigned short xbuf[2][SCH * DD];   // 2 x 16 KB bf16, XOR-swz
  __shared__ __align__(16) float ubuf[2][SCH][112];            // 2 x 7 KB fp32 (pad 96->112)

  // XCD-aware mapping: all 16 d-groups of a batch live on one XCD (x fetched
  // once per L2). Round-robin blockIdx%8 -> xcd owns b in [xcd*4, xcd*4+4).
  const int n   = blockIdx.x;                  // 512 blocks
  const int xcd = n & 7;
  const int idx = n >> 3;                      // 0..63
  const int b   = xcd * 4 + (idx >> 4);        // 0..31
  const int d0  = (idx & 15) << 5;             // 0,32,..,480

  const int wv   = threadIdx.x >> 6;
  const int lane = threadIdx.x & 63;

  if (wv < 6) {
    // ================= GEMM waves: wave wv owns n-tile wv ==================
    const int quad = lane >> 4;                // 0..3 (k-group / C row-group)
    const int l16  = lane & 15;                // A row = timestep; B row = n-col
    // --- W-frag preload (stationary, 64 VGPR): n' = wv*16+l16, g=n'>>5 ---
    bf16x8 wfrag[16];
    {
      const int row = (wv >> 1) * DD + d0 + (wv & 1) * 16 + l16;  // Wt row
      const unsigned short* wp = Wt + (size_t)row * KK + quad * 8;
#pragma unroll
      for (int j = 0; j < 16; ++j)
        wfrag[j] = *(const bf16x8*)(wp + j * 32);
    }
    const int gl    = wv * 64 + lane;          // 0..383 staging lane id
    const int abase = l16 * 1024;              // A-frag row byte base
    const int aswz  = (l16 & 7) << 4;          // read-side XOR

    for (int s = 0; s <= NCH + 1; ++s) {
      // ---- (1) issue global loads for x-chunk s (latency hides under MFMA)
      float4 st0a, st0b, st1a, st1b, st2a, st2b;
      const bool do_stage = (s < NCH);
      const bool t2 = (gl < 256);              // 1024 16B-blocks over 384 lanes
      if (do_stage) {
        {
          int row = gl >> 6, c16 = gl & 63;
          const float* sp = x + ((size_t)(s * SCH + row) * BB + b) * DD + c16 * 8;
          st0a = *(const float4*)sp; st0b = *(const float4*)(sp + 4);
        }
        {
          int bid = 384 + gl; int row = bid >> 6, c16 = bid & 63;
          const float* sp = x + ((size_t)(s * SCH + row) * BB + b) * DD + c16 * 8;
          st1a = *(const float4*)sp; st1b = *(const float4*)(sp + 4);
        }
        if (t2) {
          int bid = 768 + gl; int row = bid >> 6, c16 = bid & 63;
          const float* sp = x + ((size_t)(s * SCH + row) * BB + b) * DD + c16 * 8;
          st2a = *(const float4*)sp; st2b = *(const float4*)(sp + 4);
        }
      }
      // ---- (2) compute U-chunk s-1 from xbuf[(s-1)&1] -> ubuf[(s-1)&1]
      if (s >= 1 && s <= NCH) {
        const char* xb = (const char*)xbuf[(s - 1) & 1];
        f32x4 acc = {};
#pragma unroll
        for (int j = 0; j < 16; ++j) {         // K = 512 = 16 k-steps
          bf16x8 af = *(const bf16x8*)(xb + abase + ((j * 64 + quad * 16) ^ aswz));
          acc = __builtin_amdgcn_mfma_f32_16x16x32_bf16(af, wfrag[j], acc, 0, 0, 0);
        }
        // C layout (verified): m = quad*4+r (timestep), n = wv*16+l16
        float* up = &ubuf[(s - 1) & 1][0][0];
#pragma unroll
        for (int r = 0; r < 4; ++r)
          up[(quad * 4 + r) * 112 + wv * 16 + l16] = acc[r];
      }
      // ---- (3) finish stage: cvt + swizzled ds_write into xbuf[s&1]
      if (do_stage) {
        char* xw = (char*)xbuf[s & 1];
        {
          int row = gl >> 6, c16 = gl & 63;
          union { bf16x8 v; unsigned short u[8]; } o;
          o.u[0]=f2bf(st0a.x); o.u[1]=f2bf(st0a.y); o.u[2]=f2bf(st0a.z); o.u[3]=f2bf(st0a.w);
          o.u[4]=f2bf(st0b.x); o.u[5]=f2bf(st0b.y); o.u[6]=f2bf(st0b.z); o.u[7]=f2bf(st0b.w);
          *(bf16x8*)(xw + row * 1024 + ((c16 * 16) ^ ((row & 7) << 4))) = o.v;
        }
        {
          int bid = 384 + gl; int row = bid >> 6, c16 = bid & 63;
          union { bf16x8 v; unsigned short u[8]; } o;
          o.u[0]=f2bf(st1a.x); o.u[1]=f2bf(st1a.y); o.u[2]=f2bf(st1a.z); o.u[3]=f2bf(st1a.w);
          o.u[4]=f2bf(st1b.x); o.u[5]=f2bf(st1b.y); o.u[6]=f2bf(st1b.z); o.u[7]=f2bf(st1b.w);
          *(bf16x8*)(xw + row * 1024 + ((c16 * 16) ^ ((row & 7) << 4))) = o.v;
        }
        if (t2) {
          int bid = 768 + gl; int row = bid >> 6, c16 = bid & 63;
          union { bf16x8 v; unsigned short u[8]; } o;
          o.u[0]=f2bf(st2a.x); o.u[1]=f2bf(st2a.y); o.u[2]=f2bf(st2a.z); o.u[3]=f2bf(st2a.w);
          o.u[4]=f2bf(st2b.x); o.u[5]=f2bf(st2b.y); o.u[6]=f2bf(st2b.z); o.u[7]=f2bf(st2b.w);
          *(bf16x8*)(xw + row * 1024 + ((c16 * 16) ^ ((row & 7) << 4))) = o.v;
        }
      }
      __syncthreads();
    }
  } else {
    // ======================= scan wave (wv == 6) ==========================
    const int ch = lane;                       // lanes 32-63 idle (guarded)
    const float kln = 1.442695040888963f;
    float pf0 = 0.f, pr0 = 0.f, pf1 = 0.f, pr1 = 0.f, c = 0.f;
    float* hp = nullptr;
    if (ch < 32) {
      const int d = d0 + ch;
      float wcf = wc[d], wcr = wc[DD + d];
      pf0 = -kln * bias[d];      pr0 = -kln * bias[DD + d];
      pf1 = -kln * wcf;          pr1 = -kln * wcr;
      hp = out + (size_t)b * DD + d;           // h[l][b][d], +B*D per step
    }
    for (int s = 0; s <= NCH + 1; ++s) {
      if (s >= 2 && ch < 32) {
        const int cc = s - 2;
        const float* ub = &ubuf[cc & 1][0][0];
        const float* xp = x + ((size_t)(cc * SCH) * BB + b) * DD + d0 + ch;  // fp32 residual
#pragma unroll
        for (int t = 0; t < SCH; ++t) {
          float u0 = ub[t * 112 + ch];         // g=0 candidate
          float u1 = ub[t * 112 + 32 + ch];    // g=1 forget
          float u2 = ub[t * 112 + 64 + ch];    // g=2 reset
          float xr = xp[(size_t)t * BB * DD];
          // sigmoid(t) = rcp(1 + exp2(-k*t))
          float tf = __builtin_fmaf(pf1, c, __builtin_fmaf(-kln, u1, pf0));
          float tr = __builtin_fmaf(pr1, c, __builtin_fmaf(-kln, u2, pr0));
          float fg = __builtin_amdgcn_rcpf(1.0f + __builtin_amdgcn_exp2f(tf));
          float rg = __builtin_amdgcn_rcpf(1.0f + __builtin_amdgcn_exp2f(tr));
          c = __builtin_fmaf(fg, c - u0, u0);
          *hp = __builtin_fmaf(rg, c - xr, xr);
          hp += BB * DD;
        }
      }
      __syncthreads();
    }
    if (ch < 32)                               // c_last, concatenated after h
      out[(size_t)LL * BB * DD + (size_t)b * DD + d0 + ch] = c;
  }
}

extern "C" void kernel_launch(void* const* d_in, const int* in_sizes, int n_in,
                              void* d_out, int out_size, void* d_ws, size_t ws_size,
                              hipStream_t stream) {
  const float* x    = (const float*)d_in[0];   // (L,B,D) fp32
  const float* W    = (const float*)d_in[1];   // (D,3D) fp32
  const float* wc   = (const float*)d_in[2];   // (2D,)  fp32
  const float* bias = (const float*)d_in[3];   // (2D,)  fp32
  float* out = (float*)d_out;                  // h (L,B,D) fp32 ++ c_last (B,D)

  unsigned short* Wt = (unsigned short*)d_ws;  // 1.5 MB bf16, only workspace use

  cvt_w_kernel<<<(NN * KK) / 256, 256, 0, stream>>>(W, Wt);
  fused_kernel<<<BB * (DD / 32), 448, 0, stream>>>(x, Wt, wc, bias, out);
}

// Round 11
// 453.800 us; speedup vs baseline: 1.7872x; 1.7872x over previous
//
#include <hip/hip_runtime.h>

// Problem constants: L=2048, B=32, D=512
#define LL 2048
#define BB 32
#define DD 512
#define NN (3 * DD)
#define KK (DD)

#define SCH 16                 /* timesteps per chunk */
#define NCH (LL / SCH)         /* 128 chunks          */

typedef short bf16x8 __attribute__((ext_vector_type(8)));
typedef float f32x4 __attribute__((ext_vector_type(4)));

__device__ __forceinline__ unsigned short f2bf(float f) {
  unsigned u = __builtin_bit_cast(unsigned, f);
  u += 0x7fffu + ((u >> 16) & 1u);   // round-to-nearest-even
  return (unsigned short)(u >> 16);
}

// ------- kernel 1: W (D x 3D fp32) -> Wt (bf16, [o'=g*D+d][k] N-major) -----
__global__ __launch_bounds__(256) void cvt_w_kernel(const float* __restrict__ W,
                                                    unsigned short* __restrict__ Wt) {
  int j = blockIdx.x * 256 + threadIdx.x;      // 786432 threads, exact
  int i  = j & (KK - 1);                       // k 0..511
  int op = j >> 9;                             // o' 0..1535
  int g  = op >> 9;                            // gate 0..2
  int dd = op & (DD - 1);                      // d 0..511
  Wt[j] = f2bf(W[(size_t)i * NN + dd * 3 + g]);
}

// ------------------- kernel 2: fused GEMM + sequential scan ----------------
// 512 blocks x 448 thr (7 waves). Block = (batch b, 32-channel group d0).
// Waves 0-5: stage x fp32->bf16 into swizzled LDS + copy this block's 32-ch
// fp32 residual slice into rbuf; MFMA U-chunk with stationary W in registers.
// Wave 6: consumes U-chunk + rbuf (2-step lag); ALL operands register-
// prefetched before the serial chain (round-7 counters: scan-path global/LDS
// latency inside the recurrence was ~12k cy/step -> 663us).
// Race audit: step s writes xbuf[s&1], ubuf[(s-1)&1], rbuf[s&3];
//             reads  xbuf[(s-1)&1], ubuf[(s-2)&1], rbuf[(s-2)&3]. Disjoint.
__global__ __launch_bounds__(448, 4) void fused_kernel(
    const float* __restrict__ x, const unsigned short* __restrict__ Wt,
    const float* __restrict__ wc, const float* __restrict__ bias,
    float* __restrict__ out) {
  __shared__ __align__(16) unsigned short xbuf[2][SCH * DD];   // 32 KB bf16, XOR-swz
  __shared__ __align__(16) float ubuf[2][SCH][112];            // 14 KB fp32 (pad 96->112)
  __shared__ __align__(16) float rbuf[4][SCH][32];             // 8 KB fp32 residual slice

  // XCD-aware mapping: all 16 d-groups of a batch on one XCD (x L2-shared).
  const int n   = blockIdx.x;                  // 512 blocks
  const int xcd = n & 7;
  const int idx = n >> 3;                      // 0..63
  const int b   = xcd * 4 + (idx >> 4);        // 0..31
  const int d0  = (idx & 15) << 5;             // 0,32,..,480

  const int wv   = threadIdx.x >> 6;
  const int lane = threadIdx.x & 63;

  if (wv < 6) {
    // ================= GEMM waves: wave wv owns n-tile wv ==================
    const int quad = lane >> 4;                // 0..3
    const int l16  = lane & 15;
    // --- W-frag preload (stationary, 64 VGPR) ---
    bf16x8 wfrag[16];
    {
      const int row = (wv >> 1) * DD + d0 + (wv & 1) * 16 + l16;  // Wt row
      const unsigned short* wp = Wt + (size_t)row * KK + quad * 8;
#pragma unroll
      for (int j = 0; j < 16; ++j)
        wfrag[j] = *(const bf16x8*)(wp + j * 32);
    }
    const int gl    = wv * 64 + lane;          // 0..383 staging lane id
    const int abase = l16 * 1024;              // A-frag row byte base
    const int aswz  = (l16 & 7) << 4;          // read-side XOR
    const int c16lo = d0 >> 3;                 // residual 8-float group base

    for (int s = 0; s <= NCH + 1; ++s) {
      // ---- (1) issue global loads for x-chunk s
      float4 st0a, st0b, st1a, st1b, st2a, st2b;
      const bool do_stage = (s < NCH);
      const bool t2 = (gl < 256);              // 1024 16B-blocks over 384 lanes
      if (do_stage) {
        {
          int row = gl >> 6, c16 = gl & 63;
          const float* sp = x + ((size_t)(s * SCH + row) * BB + b) * DD + c16 * 8;
          st0a = *(const float4*)sp; st0b = *(const float4*)(sp + 4);
        }
        {
          int bid = 384 + gl; int row = bid >> 6, c16 = bid & 63;
          const float* sp = x + ((size_t)(s * SCH + row) * BB + b) * DD + c16 * 8;
          st1a = *(const float4*)sp; st1b = *(const float4*)(sp + 4);
        }
        if (t2) {
          int bid = 768 + gl; int row = bid >> 6, c16 = bid & 63;
          const float* sp = x + ((size_t)(s * SCH + row) * BB + b) * DD + c16 * 8;
          st2a = *(const float4*)sp; st2b = *(const float4*)(sp + 4);
        }
      }
      // ---- (2) compute U-chunk s-1 from xbuf[(s-1)&1] -> ubuf[(s-1)&1]
      if (s >= 1 && s <= NCH) {
        const char* xb = (const char*)xbuf[(s - 1) & 1];
        f32x4 acc = {};
#pragma unroll
        for (int j = 0; j < 16; ++j) {         // K = 512 = 16 k-steps
          bf16x8 af = *(const bf16x8*)(xb + abase + ((j * 64 + quad * 16) ^ aswz));
          acc = __builtin_amdgcn_mfma_f32_16x16x32_bf16(af, wfrag[j], acc, 0, 0, 0);
        }
        float* up = &ubuf[(s - 1) & 1][0][0];
#pragma unroll
        for (int r = 0; r < 4; ++r)
          up[(quad * 4 + r) * 112 + wv * 16 + l16] = acc[r];
      }
      // ---- (3) finish stage: rbuf fp32 slice + cvt + swizzled xbuf writes
      if (do_stage) {
        char*  xw = (char*)xbuf[s & 1];
        float* rw = &rbuf[s & 3][0][0];
        {
          int row = gl >> 6, c16 = gl & 63;
          int cg = c16 - c16lo;
          if ((unsigned)cg < 4u) {
            *(float4*)&rw[row * 32 + cg * 8]     = st0a;
            *(float4*)&rw[row * 32 + cg * 8 + 4] = st0b;
          }
          union { bf16x8 v; unsigned short u[8]; } o;
          o.u[0]=f2bf(st0a.x); o.u[1]=f2bf(st0a.y); o.u[2]=f2bf(st0a.z); o.u[3]=f2bf(st0a.w);
          o.u[4]=f2bf(st0b.x); o.u[5]=f2bf(st0b.y); o.u[6]=f2bf(st0b.z); o.u[7]=f2bf(st0b.w);
          *(bf16x8*)(xw + row * 1024 + ((c16 * 16) ^ ((row & 7) << 4))) = o.v;
        }
        {
          int bid = 384 + gl; int row = bid >> 6, c16 = bid & 63;
          int cg = c16 - c16lo;
          if ((unsigned)cg < 4u) {
            *(float4*)&rw[row * 32 + cg * 8]     = st1a;
            *(float4*)&rw[row * 32 + cg * 8 + 4] = st1b;
          }
          union { bf16x8 v; unsigned short u[8]; } o;
          o.u[0]=f2bf(st1a.x); o.u[1]=f2bf(st1a.y); o.u[2]=f2bf(st1a.z); o.u[3]=f2bf(st1a.w);
          o.u[4]=f2bf(st1b.x); o.u[5]=f2bf(st1b.y); o.u[6]=f2bf(st1b.z); o.u[7]=f2bf(st1b.w);
          *(bf16x8*)(xw + row * 1024 + ((c16 * 16) ^ ((row & 7) << 4))) = o.v;
        }
        if (t2) {
          int bid = 768 + gl; int row = bid >> 6, c16 = bid & 63;
          int cg = c16 - c16lo;
          if ((unsigned)cg < 4u) {
            *(float4*)&rw[row * 32 + cg * 8]     = st2a;
            *(float4*)&rw[row * 32 + cg * 8 + 4] = st2b;
          }
          union { bf16x8 v; unsigned short u[8]; } o;
          o.u[0]=f2bf(st2a.x); o.u[1]=f2bf(st2a.y); o.u[2]=f2bf(st2a.z); o.u[3]=f2bf(st2a.w);
          o.u[4]=f2bf(st2b.x); o.u[5]=f2bf(st2b.y); o.u[6]=f2bf(st2b.z); o.u[7]=f2bf(st2b.w);
          *(bf16x8*)(xw + row * 1024 + ((c16 * 16) ^ ((row & 7) << 4))) = o.v;
        }
      }
      __syncthreads();
    }
  } else {
    // ======================= scan wave (wv == 6) ==========================
    const int ch = lane;                       // lanes 32-63 idle (guarded)
    const float kln = 1.442695040888963f;
    float pf0 = 0.f, pr0 = 0.f, pf1 = 0.f, pr1 = 0.f, c = 0.f;
    float* hp = nullptr;
    if (ch < 32) {
      const int d = d0 + ch;
      float wcf = wc[d], wcr = wc[DD + d];
      pf0 = -kln * bias[d];      pr0 = -kln * bias[DD + d];
      pf1 = -kln * wcf;          pr1 = -kln * wcr;
      hp = out + (size_t)b * DD + d;           // h[l][b][d], +B*D per step
    }
    for (int s = 0; s <= NCH + 1; ++s) {
      if (s >= 2 && ch < 32) {
        const int cc = s - 2;
        const float* ub = &ubuf[cc & 1][0][0];
        const float* rb = &rbuf[cc & 3][0][0];
        // register-prefetch ALL chunk operands (static indices -> VGPRs)
        float u0v[SCH], u1v[SCH], u2v[SCH], xrv[SCH];
#pragma unroll
        for (int t = 0; t < SCH; ++t) {
          u0v[t] = ub[t * 112 + ch];
          u1v[t] = ub[t * 112 + 32 + ch];
          u2v[t] = ub[t * 112 + 64 + ch];
          xrv[t] = rb[t * 32 + ch];
        }
#pragma unroll
        for (int t = 0; t < SCH; ++t) {
          // sigmoid(t) = rcp(1 + exp2(-k*t))
          float tf = __builtin_fmaf(pf1, c, __builtin_fmaf(-kln, u1v[t], pf0));
          float tr = __builtin_fmaf(pr1, c, __builtin_fmaf(-kln, u2v[t], pr0));
          float fg = __builtin_amdgcn_rcpf(1.0f + __builtin_amdgcn_exp2f(tf));
          float rg = __builtin_amdgcn_rcpf(1.0f + __builtin_amdgcn_exp2f(tr));
          c = __builtin_fmaf(fg, c - u0v[t], u0v[t]);
          *hp = __builtin_fmaf(rg, c - xrv[t], xrv[t]);
          hp += BB * DD;
        }
      }
      __syncthreads();
    }
    if (ch < 32)                               // c_last, concatenated after h
      out[(size_t)LL * BB * DD + (size_t)b * DD + d0 + ch] = c;
  }
}

extern "C" void kernel_launch(void* const* d_in, const int* in_sizes, int n_in,
                              void* d_out, int out_size, void* d_ws, size_t ws_size,
                              hipStream_t stream) {
  const float* x    = (const float*)d_in[0];   // (L,B,D) fp32
  const float* W    = (const float*)d_in[1];   // (D,3D) fp32
  const float* wc   = (const float*)d_in[2];   // (2D,)  fp32
  const float* bias = (const float*)d_in[3];   // (2D,)  fp32
  float* out = (float*)d_out;                  // h (L,B,D) fp32 ++ c_last (B,D)

  unsigned short* Wt = (unsigned short*)d_ws;  // 1.5 MB bf16, only workspace use

  cvt_w_kernel<<<(NN * KK) / 256, 256, 0, stream>>>(W, Wt);
  fused_kernel<<<BB * (DD / 32), 448, 0, stream>>>(x, Wt, wc, bias, out);
}

// Round 12
// 412.109 us; speedup vs baseline: 1.9680x; 1.1012x over previous
//
#include <hip/hip_runtime.h>

// Problem constants: L=2048, B=32, D=512
#define LL 2048
#define BB 32
#define DD 512
#define NN (3 * DD)
#define KK (DD)

#define SCH 16                 /* timesteps per chunk */
#define NCH (LL / SCH)         /* 128 chunks          */
#define TP 20                  /* padded t-dim of ubt (bank-spread, 5*16B)  */

typedef short bf16x8 __attribute__((ext_vector_type(8)));
typedef float f32x4 __attribute__((ext_vector_type(4)));

__device__ __forceinline__ unsigned short f2bf(float f) {
  unsigned u = __builtin_bit_cast(unsigned, f);
  u += 0x7fffu + ((u >> 16) & 1u);   // round-to-nearest-even
  return (unsigned short)(u >> 16);
}

// ------- kernel 1: W (D x 3D fp32) -> Wt (bf16, [o'=g*D+d][k] N-major) -----
__global__ __launch_bounds__(256) void cvt_w_kernel(const float* __restrict__ W,
                                                    unsigned short* __restrict__ Wt) {
  int j = blockIdx.x * 256 + threadIdx.x;      // 786432 threads, exact
  int i  = j & (KK - 1);                       // k 0..511
  int op = j >> 9;                             // o' 0..1535
  int g  = op >> 9;                            // gate 0..2
  int dd = op & (DD - 1);                      // d 0..511
  Wt[j] = f2bf(W[(size_t)i * NN + dd * 3 + g]);
}

// ------------------- kernel 2: fused GEMM + sequential scan ----------------
// 512 blocks x 256 thr (4 waves). Block = (batch b, 32-channel group d0).
// R11 counters: LDS pipe was the bottleneck (6 waves x 16 ds_read_b128 all
// re-reading the same A-tile = ~2300-3600 cy/step of 5690 measured).
// Now: 3 GEMM waves, each owns ONE GATE (2 n-tiles) -> one A-frag read feeds
// 2 MFMAs (A-read instrs halved). ubt transposed to [gate][ch][t(pad 20)] so
// the f32x4 acc stores as ONE b128 and scan reads 12 b128 instead of 48 b32.
// Race audit (per super-step s): writes xbuf[s&1], ubt[(s-1)&1], rbuf[s&3];
// reads xbuf[(s-1)&1], ubt[(s-2)&1], rbuf[(s-2)&3] — all disjoint; one
// barrier per step; both branches execute NCH+2 barriers.
__global__ __launch_bounds__(256, 2) void fused_kernel(
    const float* __restrict__ x, const unsigned short* __restrict__ Wt,
    const float* __restrict__ wc, const float* __restrict__ bias,
    float* __restrict__ out) {
  __shared__ __align__(16) unsigned short xbuf[2][SCH * DD];   // 32 KB bf16, XOR-swz
  __shared__ __align__(16) float ubt[2][3][32][TP];            // 15.36 KB fp32
  __shared__ __align__(16) float rbuf[4][SCH][32];             // 8 KB fp32 residual

  // XCD-aware mapping: all 16 d-groups of a batch on one XCD (x L2-shared).
  const int n   = blockIdx.x;                  // 512 blocks
  const int xcd = n & 7;
  const int idx = n >> 3;                      // 0..63
  const int b   = xcd * 4 + (idx >> 4);        // 0..31
  const int d0  = (idx & 15) << 5;             // 0,32,..,480

  const int wv   = threadIdx.x >> 6;
  const int lane = threadIdx.x & 63;

  if (wv < 3) {
    // ========== GEMM waves: wave wv owns gate wv (cols wv*32..wv*32+31) ====
    const int quad = lane >> 4;                // 0..3 (k-group / C t-group)
    const int l16  = lane & 15;
    // --- W-frags, stationary: tile0 cols l16, tile1 cols 16+l16 (128 VGPR)
    bf16x8 wf0[16], wf1[16];
    {
      const unsigned short* wp0 = Wt + (size_t)(wv * DD + d0 + l16) * KK + quad * 8;
      const unsigned short* wp1 = wp0 + (size_t)16 * KK;
#pragma unroll
      for (int j = 0; j < 16; ++j) {
        wf0[j] = *(const bf16x8*)(wp0 + j * 32);
        wf1[j] = *(const bf16x8*)(wp1 + j * 32);
      }
    }
    const int gl    = wv * 64 + lane;          // 0..191 staging lane id
    const int abase = l16 * 1024;              // A-frag row byte base
    const int aswz  = (l16 & 7) << 4;          // read-side XOR
    const int c16lo = d0 >> 3;                 // residual 8-float group base

    for (int s = 0; s <= NCH + 1; ++s) {
      // ---- (1) issue global loads for x-chunk s (6 bids/lane, 1024 total)
      float4 sa[6], sb[6];
      const bool do_stage = (s < NCH);
      const bool t6 = (gl < 64);
      if (do_stage) {
#pragma unroll
        for (int i = 0; i < 5; ++i) {
          int bid = gl + 192 * i;              // 0..959
          int row = bid >> 6, c16 = bid & 63;
          const float* sp = x + ((size_t)(s * SCH + row) * BB + b) * DD + c16 * 8;
          sa[i] = *(const float4*)sp; sb[i] = *(const float4*)(sp + 4);
        }
        if (t6) {
          int bid = 960 + gl;                  // 960..1023
          int row = bid >> 6, c16 = bid & 63;
          const float* sp = x + ((size_t)(s * SCH + row) * BB + b) * DD + c16 * 8;
          sa[5] = *(const float4*)sp; sb[5] = *(const float4*)(sp + 4);
        }
      }
      // ---- (2) compute U-chunk s-1: one A-read feeds BOTH tiles
      if (s >= 1 && s <= NCH) {
        const char* xb = (const char*)xbuf[(s - 1) & 1];
        f32x4 acc0 = {}, acc1 = {};
#pragma unroll
        for (int j = 0; j < 16; ++j) {         // K = 512 = 16 k-steps
          bf16x8 af = *(const bf16x8*)(xb + abase + ((j * 64 + quad * 16) ^ aswz));
          acc0 = __builtin_amdgcn_mfma_f32_16x16x32_bf16(af, wf0[j], acc0, 0, 0, 0);
          acc1 = __builtin_amdgcn_mfma_f32_16x16x32_bf16(af, wf1[j], acc1, 0, 0, 0);
        }
        // C layout: t = quad*4+r contiguous -> single b128 store per tile
        float* ug = &ubt[(s - 1) & 1][wv][0][0];
        *(f32x4*)&ug[l16 * TP + quad * 4]        = acc0;
        *(f32x4*)&ug[(16 + l16) * TP + quad * 4] = acc1;
      }
      // ---- (3) finish stage: rbuf fp32 slice + cvt + swizzled xbuf writes
      if (do_stage) {
        char*  xw = (char*)xbuf[s & 1];
        float* rw = &rbuf[s & 3][0][0];
#pragma unroll
        for (int i = 0; i < 5; ++i) {
          int bid = gl + 192 * i;
          int row = bid >> 6, c16 = bid & 63;
          int cg = c16 - c16lo;
          if ((unsigned)cg < 4u) {
            *(float4*)&rw[row * 32 + cg * 8]     = sa[i];
            *(float4*)&rw[row * 32 + cg * 8 + 4] = sb[i];
          }
          union { bf16x8 v; unsigned short u[8]; } o;
          o.u[0]=f2bf(sa[i].x); o.u[1]=f2bf(sa[i].y); o.u[2]=f2bf(sa[i].z); o.u[3]=f2bf(sa[i].w);
          o.u[4]=f2bf(sb[i].x); o.u[5]=f2bf(sb[i].y); o.u[6]=f2bf(sb[i].z); o.u[7]=f2bf(sb[i].w);
          *(bf16x8*)(xw + row * 1024 + ((c16 * 16) ^ ((row & 7) << 4))) = o.v;
        }
        if (t6) {
          int bid = 960 + gl;
          int row = bid >> 6, c16 = bid & 63;
          int cg = c16 - c16lo;
          if ((unsigned)cg < 4u) {
            *(float4*)&rw[row * 32 + cg * 8]     = sa[5];
            *(float4*)&rw[row * 32 + cg * 8 + 4] = sb[5];
          }
          union { bf16x8 v; unsigned short u[8]; } o;
          o.u[0]=f2bf(sa[5].x); o.u[1]=f2bf(sa[5].y); o.u[2]=f2bf(sa[5].z); o.u[3]=f2bf(sa[5].w);
          o.u[4]=f2bf(sb[5].x); o.u[5]=f2bf(sb[5].y); o.u[6]=f2bf(sb[5].z); o.u[7]=f2bf(sb[5].w);
          *(bf16x8*)(xw + row * 1024 + ((c16 * 16) ^ ((row & 7) << 4))) = o.v;
        }
      }
      __syncthreads();
    }
  } else {
    // ======================= scan wave (wv == 3) ==========================
    const int ch = lane;                       // lanes 32-63 idle (guarded)
    const float kln = 1.442695040888963f;
    float pf0 = 0.f, pr0 = 0.f, pf1 = 0.f, pr1 = 0.f, c = 0.f;
    float* hp = nullptr;
    if (ch < 32) {
      const int d = d0 + ch;
      float wcf = wc[d], wcr = wc[DD + d];
      pf0 = -kln * bias[d];      pr0 = -kln * bias[DD + d];
      pf1 = -kln * wcf;          pr1 = -kln * wcr;
      hp = out + (size_t)b * DD + d;           // h[l][b][d], +B*D per step
    }
    for (int s = 0; s <= NCH + 1; ++s) {
      if (s >= 2 && ch < 32) {
        const int cc = s - 2;
        const float* ub = &ubt[cc & 1][0][0][0];   // gate stride 32*TP=640 f
        const float* rb = &rbuf[cc & 3][0][0];
        // register-prefetch all operands; ubt reads are b128 (t-contiguous)
        float u0v[SCH], u1v[SCH], u2v[SCH], xrv[SCH];
#pragma unroll
        for (int j = 0; j < 4; ++j) {
          float4 q0 = *(const float4*)&ub[        ch * TP + j * 4];
          float4 q1 = *(const float4*)&ub[ 640 +  ch * TP + j * 4];
          float4 q2 = *(const float4*)&ub[1280 +  ch * TP + j * 4];
          u0v[j*4+0]=q0.x; u0v[j*4+1]=q0.y; u0v[j*4+2]=q0.z; u0v[j*4+3]=q0.w;
          u1v[j*4+0]=q1.x; u1v[j*4+1]=q1.y; u1v[j*4+2]=q1.z; u1v[j*4+3]=q1.w;
          u2v[j*4+0]=q2.x; u2v[j*4+1]=q2.y; u2v[j*4+2]=q2.z; u2v[j*4+3]=q2.w;
        }
#pragma unroll
        for (int t = 0; t < SCH; ++t) xrv[t] = rb[t * 32 + ch];
#pragma unroll
        for (int t = 0; t < SCH; ++t) {
          // sigmoid(t) = rcp(1 + exp2(-k*t))
          float tf = __builtin_fmaf(pf1, c, __builtin_fmaf(-kln, u1v[t], pf0));
          float tr = __builtin_fmaf(pr1, c, __builtin_fmaf(-kln, u2v[t], pr0));
          float fg = __builtin_amdgcn_rcpf(1.0f + __builtin_amdgcn_exp2f(tf));
          float rg = __builtin_amdgcn_rcpf(1.0f + __builtin_amdgcn_exp2f(tr));
          c = __builtin_fmaf(fg, c - u0v[t], u0v[t]);
          *hp = __builtin_fmaf(rg, c - xrv[t], xrv[t]);
          hp += BB * DD;
        }
      }
      __syncthreads();
    }
    if (ch < 32)                               // c_last, concatenated after h
      out[(size_t)LL * BB * DD + (size_t)b * DD + d0 + ch] = c;
  }
}

extern "C" void kernel_launch(void* const* d_in, const int* in_sizes, int n_in,
                              void* d_out, int out_size, void* d_ws, size_t ws_size,
                              hipStream_t stream) {
  const float* x    = (const float*)d_in[0];   // (L,B,D) fp32
  const float* W    = (const float*)d_in[1];   // (D,3D) fp32
  const float* wc   = (const float*)d_in[2];   // (2D,)  fp32
  const float* bias = (const float*)d_in[3];   // (2D,)  fp32
  float* out = (float*)d_out;                  // h (L,B,D) fp32 ++ c_last (B,D)

  unsigned short* Wt = (unsigned short*)d_ws;  // 1.5 MB bf16, only workspace use

  cvt_w_kernel<<<(NN * KK) / 256, 256, 0, stream>>>(W, Wt);
  fused_kernel<<<BB * (DD / 32), 256, 0, stream>>>(x, Wt, wc, bias, out);
}

// Round 15
// 383.174 us; speedup vs baseline: 2.1166x; 1.0755x over previous
//
#include <hip/hip_runtime.h>

// Problem constants: L=2048, B=32, D=512
#define LL 2048
#define BB 32
#define DD 512
#define NN (3 * DD)
#define KK (DD)

#define SCH 16                 /* timesteps per chunk */
#define NCH (LL / SCH)         /* 128 chunks          */
#define TP 20                  /* padded t-dim of ubt (5*16B)               */

typedef short bf16x8 __attribute__((ext_vector_type(8)));
typedef float f32x4 __attribute__((ext_vector_type(4)));

__device__ __forceinline__ unsigned short f2bf(float f) {
  unsigned u = __builtin_bit_cast(unsigned, f);
  u += 0x7fffu + ((u >> 16) & 1u);   // round-to-nearest-even
  return (unsigned short)(u >> 16);
}

// ------- kernel 1: W (D x 3D fp32) -> Wt (bf16, [o'=g*D+d][k] N-major) -----
// R12: old version read W with 6KB lane stride (uncoalesced). Now 64x64
// LDS-transpose tiles: coalesced row loads, padded [64][65] column reads
// (bank-free), 128B-contiguous bf16 row writes.
__global__ __launch_bounds__(256) void cvt_w_kernel(const float* __restrict__ W,
                                                    unsigned short* __restrict__ Wt) {
  __shared__ float tile[64][65];
  const int k0  = (blockIdx.x & 7) * 64;       // 8 k-tiles
  const int o0  = (blockIdx.x >> 3) * 64;      // 24 o-tiles
  const int tid = threadIdx.x;
#pragma unroll
  for (int i = 0; i < 16; ++i) {
    int flat = i * 256 + tid;
    int kk = flat >> 6, oo = flat & 63;
    tile[kk][oo] = W[(size_t)(k0 + kk) * NN + o0 + oo];
  }
  __syncthreads();
#pragma unroll
  for (int i = 0; i < 16; ++i) {
    int flat = i * 256 + tid;
    int oo = flat >> 6, kk = flat & 63;        // wave: fixed oo, kk=lane
    int o  = o0 + oo;
    int g  = o - 3 * (o / 3);                  // o = dd*3 + g
    int dd = o / 3;
    Wt[(size_t)(g * DD + dd) * KK + k0 + kk] = f2bf(tile[kk][oo]);
  }
}

// ------------------- kernel 2: fused GEMM + sequential scan ----------------
// 512 blocks x 256 thr (4 waves). Block = (batch b, 32-channel group d0).
// R12 counters: 4870 cy/step; ~2450 = LDS pipe (structural), ~500-900 =
// vmcnt stall (loads issued phase1, consumed phase3, only ~400cy cover).
// Now: loads for chunk s+1 issue at step s into loop-carried regs; LDS write
// happens at step s+1 -> a FULL step (~2500cy) of latency cover.
// Step s: WRITE(chunk s: regs->xbuf[s&1],rbuf[s&3]) ; ISSUE(chunk s+1) ;
//         MFMA(chunk s-1: xbuf[(s-1)&1]->ubt[(s-1)&1]) ; barrier.
// Scan at step s reads ubt[(s-2)&1] (written step s-1), rbuf[(s-2)&3].
// All buffer parities disjoint per step; barrier-ordered; both branches
// execute NCH+2 barriers.
__global__ __launch_bounds__(256, 2) void fused_kernel(
    const float* __restrict__ x, const unsigned short* __restrict__ Wt,
    const float* __restrict__ wc, const float* __restrict__ bias,
    float* __restrict__ out) {
  __shared__ __align__(16) unsigned short xbuf[2][SCH * DD];   // 32 KB bf16, XOR-swz
  __shared__ __align__(16) float ubt[2][3][32][TP];            // 15.36 KB fp32
  __shared__ __align__(16) float rbuf[4][SCH][32];             // 8 KB fp32 residual

  // XCD-aware mapping: all 16 d-groups of a batch on one XCD (x L2-shared).
  const int n   = blockIdx.x;                  // 512 blocks
  const int xcd = n & 7;
  const int idx = n >> 3;                      // 0..63
  const int b   = xcd * 4 + (idx >> 4);        // 0..31
  const int d0  = (idx & 15) << 5;             // 0,32,..,480

  const int wv   = threadIdx.x >> 6;
  const int lane = threadIdx.x & 63;

  if (wv < 3) {
    // ========== GEMM waves: wave wv owns gate wv (cols wv*32..wv*32+31) ====
    const int quad = lane >> 4;                // 0..3 (k-group / C t-group)
    const int l16  = lane & 15;
    // --- W-frags, stationary: tile0 cols l16, tile1 cols 16+l16 (128 VGPR)
    bf16x8 wf0[16], wf1[16];
    {
      const unsigned short* wp0 = Wt + (size_t)(wv * DD + d0 + l16) * KK + quad * 8;
      const unsigned short* wp1 = wp0 + (size_t)16 * KK;
#pragma unroll
      for (int j = 0; j < 16; ++j) {
        wf0[j] = *(const bf16x8*)(wp0 + j * 32);
        wf1[j] = *(const bf16x8*)(wp1 + j * 32);
      }
    }
    const int gl    = wv * 64 + lane;          // 0..191 staging lane id
    const int abase = l16 * 1024;              // A-frag row byte base
    const int aswz  = (l16 & 7) << 4;          // read-side XOR
    const int c16lo = d0 >> 3;                 // residual 8-float group base
    const bool t6   = (gl < 64);

    float4 sa[6], sb[6];                       // loop-carried staging regs

#define ISSUE(ch)                                                            \
    do {                                                                     \
      _Pragma("unroll") for (int i = 0; i < 5; ++i) {                        \
        int bid = gl + 192 * i;                                              \
        int row = bid >> 6, c16 = bid & 63;                                  \
        const float* sp = x + ((size_t)((ch) * SCH + row) * BB + b) * DD + c16 * 8; \
        sa[i] = *(const float4*)sp; sb[i] = *(const float4*)(sp + 4);        \
      }                                                                      \
      if (t6) {                                                              \
        int bid = 960 + gl; int row = bid >> 6, c16 = bid & 63;              \
        const float* sp = x + ((size_t)((ch) * SCH + row) * BB + b) * DD + c16 * 8; \
        sa[5] = *(const float4*)sp; sb[5] = *(const float4*)(sp + 4);        \
      }                                                                      \
    } while (0)

#define WRITE(ch)                                                            \
    do {                                                                     \
      char*  xw = (char*)xbuf[(ch) & 1];                                     \
      float* rw = &rbuf[(ch) & 3][0][0];                                     \
      _Pragma("unroll") for (int i = 0; i < 5; ++i) {                        \
        int bid = gl + 192 * i;                                              \
        int row = bid >> 6, c16 = bid & 63;                                  \
        int cg = c16 - c16lo;                                                \
        if ((unsigned)cg < 4u) {                                             \
          *(float4*)&rw[row * 32 + cg * 8]     = sa[i];                      \
          *(float4*)&rw[row * 32 + cg * 8 + 4] = sb[i];                      \
        }                                                                    \
        union { bf16x8 v; unsigned short u[8]; } o;                          \
        o.u[0]=f2bf(sa[i].x); o.u[1]=f2bf(sa[i].y); o.u[2]=f2bf(sa[i].z); o.u[3]=f2bf(sa[i].w); \
        o.u[4]=f2bf(sb[i].x); o.u[5]=f2bf(sb[i].y); o.u[6]=f2bf(sb[i].z); o.u[7]=f2bf(sb[i].w); \
        *(bf16x8*)(xw + row * 1024 + ((c16 * 16) ^ ((row & 7) << 4))) = o.v; \
      }                                                                      \
      if (t6) {                                                              \
        int bid = 960 + gl;                                                  \
        int row = bid >> 6, c16 = bid & 63;                                  \
        int cg = c16 - c16lo;                                                \
        if ((unsigned)cg < 4u) {                                             \
          *(float4*)&rw[row * 32 + cg * 8]     = sa[5];                      \
          *(float4*)&rw[row * 32 + cg * 8 + 4] = sb[5];                      \
        }                                                                    \
        union { bf16x8 v; unsigned short u[8]; } o;                          \
        o.u[0]=f2bf(sa[5].x); o.u[1]=f2bf(sa[5].y); o.u[2]=f2bf(sa[5].z); o.u[3]=f2bf(sa[5].w); \
        o.u[4]=f2bf(sb[5].x); o.u[5]=f2bf(sb[5].y); o.u[6]=f2bf(sb[5].z); o.u[7]=f2bf(sb[5].w); \
        *(bf16x8*)(xw + row * 1024 + ((c16 * 16) ^ ((row & 7) << 4))) = o.v; \
      }                                                                      \
    } while (0)

    ISSUE(0);                                  // prologue: chunk 0 in flight
    for (int s = 0; s <= NCH + 1; ++s) {
      if (s < NCH) WRITE(s);                   // vmcnt covered by full step
      if (s + 1 < NCH) ISSUE(s + 1);           // next chunk into (renamed) regs
      if (s >= 1 && s <= NCH) {                // MFMA chunk s-1
        const char* xb = (const char*)xbuf[(s - 1) & 1];
        f32x4 acc0 = {}, acc1 = {};
#pragma unroll
        for (int j = 0; j < 16; ++j) {         // K = 512 = 16 k-steps
          bf16x8 af = *(const bf16x8*)(xb + abase + ((j * 64 + quad * 16) ^ aswz));
          acc0 = __builtin_amdgcn_mfma_f32_16x16x32_bf16(af, wf0[j], acc0, 0, 0, 0);
          acc1 = __builtin_amdgcn_mfma_f32_16x16x32_bf16(af, wf1[j], acc1, 0, 0, 0);
        }
        float* ug = &ubt[(s - 1) & 1][wv][0][0];
        *(f32x4*)&ug[l16 * TP + quad * 4]        = acc0;
        *(f32x4*)&ug[(16 + l16) * TP + quad * 4] = acc1;
      }
      __syncthreads();
    }
#undef ISSUE
#undef WRITE
  } else {
    // ======================= scan wave (wv == 3) ==========================
    const int ch = lane;                       // lanes 32-63 idle (guarded)
    const float kln = 1.442695040888963f;
    float pf0 = 0.f, pr0 = 0.f, pf1 = 0.f, pr1 = 0.f, c = 0.f;
    float* hp = nullptr;
    if (ch < 32) {
      const int d = d0 + ch;
      float wcf = wc[d], wcr = wc[DD + d];
      pf0 = -kln * bias[d];      pr0 = -kln * bias[DD + d];
      pf1 = -kln * wcf;          pr1 = -kln * wcr;
      hp = out + (size_t)b * DD + d;           // h[l][b][d], +B*D per step
    }
    for (int s = 0; s <= NCH + 1; ++s) {
      if (s >= 2 && ch < 32) {
        const int cc = s - 2;
        const float* ub = &ubt[cc & 1][0][0][0];   // gate stride 32*TP=640 f
        const float* rb = &rbuf[cc & 3][0][0];
        float u0v[SCH], u1v[SCH], u2v[SCH], xrv[SCH];
#pragma unroll
        for (int j = 0; j < 4; ++j) {
          float4 q0 = *(const float4*)&ub[        ch * TP + j * 4];
          float4 q1 = *(const float4*)&ub[ 640 +  ch * TP + j * 4];
          float4 q2 = *(const float4*)&ub[1280 +  ch * TP + j * 4];
          u0v[j*4+0]=q0.x; u0v[j*4+1]=q0.y; u0v[j*4+2]=q0.z; u0v[j*4+3]=q0.w;
          u1v[j*4+0]=q1.x; u1v[j*4+1]=q1.y; u1v[j*4+2]=q1.z; u1v[j*4+3]=q1.w;
          u2v[j*4+0]=q2.x; u2v[j*4+1]=q2.y; u2v[j*4+2]=q2.z; u2v[j*4+3]=q2.w;
        }
#pragma unroll
        for (int t = 0; t < SCH; ++t) xrv[t] = rb[t * 32 + ch];
#pragma unroll
        for (int t = 0; t < SCH; ++t) {
          // sigmoid(t) = rcp(1 + exp2(-k*t))
          float tf = __builtin_fmaf(pf1, c, __builtin_fmaf(-kln, u1v[t], pf0));
          float tr = __builtin_fmaf(pr1, c, __builtin_fmaf(-kln, u2v[t], pr0));
          float fg = __builtin_amdgcn_rcpf(1.0f + __builtin_amdgcn_exp2f(tf));
          float rg = __builtin_amdgcn_rcpf(1.0f + __builtin_amdgcn_exp2f(tr));
          c = __builtin_fmaf(fg, c - u0v[t], u0v[t]);
          *hp = __builtin_fmaf(rg, c - xrv[t], xrv[t]);
          hp += BB * DD;
        }
      }
      __syncthreads();
    }
    if (ch < 32)                               // c_last, concatenated after h
      out[(size_t)LL * BB * DD + (size_t)b * DD + d0 + ch] = c;
  }
}

extern "C" void kernel_launch(void* const* d_in, const int* in_sizes, int n_in,
                              void* d_out, int out_size, void* d_ws, size_t ws_size,
                              hipStream_t stream) {
  const float* x    = (const float*)d_in[0];   // (L,B,D) fp32
  const float* W    = (const float*)d_in[1];   // (D,3D) fp32
  const float* wc   = (const float*)d_in[2];   // (2D,)  fp32
  const float* bias = (const float*)d_in[3];   // (2D,)  fp32
  float* out = (float*)d_out;                  // h (L,B,D) fp32 ++ c_last (B,D)

  unsigned short* Wt = (unsigned short*)d_ws;  // 1.5 MB bf16, only workspace use

  cvt_w_kernel<<<8 * 24, 256, 0, stream>>>(W, Wt);
  fused_kernel<<<BB * (DD / 32), 256, 0, stream>>>(x, Wt, wc, bias, out);
}